// Round 8
// baseline (244.075 us; speedup 1.0000x reference)
//
#include <hip/hip_runtime.h>
#include <hip/hip_bf16.h>

// CombinedGeomAttention, ALPHA=1:
//   s = 0.125*sqrt(relu(|q|^2|k|^2 - (q.k)^2) + 1e-8); out0 = softmax_s(s) @ V; out1 = mean(s)
// Round 8: barrier-free attention, 256-thread blocks with 4 INDEPENDENT waves
// (one 16-row q-tile each, zero __syncthreads). K/V MFMA fragments loaded
// directly from pre-packed L2-resident Kg/Vg (no LDS staging); wave-private P
// only (2KB/wave). Register lifetimes staged: K-frags die before V-frags load.

#define B_ 4
#define L_ 2048
#define S_ 2048
#define H_ 8
#define E_ 64
#define EPS_ 1e-8f
#define SC2_ 0.18033688011112042f   // 0.125 * log2(e)
#define LN2_ 0.6931471805599453f
#define ROWSTR (H_ * E_)            // 512 floats
#define NOUT ((size_t)B_ * L_ * H_ * E_)

#define K_OFF 0
#define V_OFF 8388608
#define KN_OFF 16777216

typedef __attribute__((ext_vector_type(8))) short bf16x8;
typedef __attribute__((ext_vector_type(4))) float f32x4;
typedef __attribute__((ext_vector_type(2))) float f32x2;

union bfr8 { bf16x8 v; unsigned u[4]; };

static __device__ __forceinline__ unsigned pk2(float lo, float hi) {
  union { __hip_bfloat162 h2; unsigned u; } cv;
  cv.h2 = __float22bfloat162_rn(float2{lo, hi});
  return cv.u;
}
static __device__ __forceinline__ unsigned cvtpk(float lo, float hi) {
  unsigned r;
  asm("v_cvt_pk_bf16_f32 %0, %1, %2" : "=v"(r) : "v"(lo), "v"(hi));
  return r;
}
static __device__ __forceinline__ float fast_sqrt(float x) {
  float r; asm("v_sqrt_f32 %0, %1" : "=v"(r) : "v"(x)); return r;
}
static __device__ __forceinline__ float fast_exp2(float x) {
  float r; asm("v_exp_f32 %0, %1" : "=v"(r) : "v"(x)); return r;
}

// ---------------- fused prepass (identical to round 6, which passed) ----------------
// K -> bf16 swizzled [bh,tile][s][e-chunks] + |k|^2 ; V -> bf16 transposed+swizzled [e][s-chunks]
__global__ void prep_kv(const float* __restrict__ K, const float* __restrict__ V,
                        short* __restrict__ Kg, short* __restrict__ Vg,
                        float* __restrict__ kn2g, float* __restrict__ out) {
  const int tid = threadIdx.x;
  const int bidx = blockIdx.x;          // bh*32 + st
  if (bidx == 0 && tid == 0) out[NOUT] = 0.f;   // zero the scalar accumulator slot
  const int st = bidx & 31;
  const int bh = bidx >> 5;
  const int b = bh >> 3, h = bh & 7;
  const size_t src_base = (size_t)b * (L_ * ROWSTR) + (size_t)(st * 64) * ROWSTR + (size_t)h * E_;

  // ---- K part
  {
    short* dst = Kg + (size_t)bidx * 4096;
    const int s = tid >> 2;
    float part = 0.f;
#pragma unroll
    for (int q = 0; q < 2; ++q) {
      const int ch = (2 * tid + q) & 7;
      const int esrc = (ch ^ (s & 7)) * 8;
      const float* sp = K + src_base + (size_t)s * ROWSTR + esrc;
      const float4 a = *reinterpret_cast<const float4*>(sp);
      const float4 c4 = *reinterpret_cast<const float4*>(sp + 4);
      part += a.x*a.x + a.y*a.y + a.z*a.z + a.w*a.w
            + c4.x*c4.x + c4.y*c4.y + c4.z*c4.z + c4.w*c4.w;
      bfr8 o;
      o.u[0] = pk2(a.x, a.y);  o.u[1] = pk2(a.z, a.w);
      o.u[2] = pk2(c4.x, c4.y); o.u[3] = pk2(c4.z, c4.w);
      *reinterpret_cast<bf16x8*>(dst + s * 64 + ch * 8) = o.v;
    }
    part += __shfl_xor(part, 1);
    part += __shfl_xor(part, 2);
    if ((tid & 3) == 0) kn2g[(size_t)bidx * 64 + s] = part;
  }

  // ---- V part (no LDS; coalesced 256B column-segment reads)
  {
    short* dst = Vg + (size_t)bidx * 4096;
    const int e = tid & 63;
    const int sc0 = tid >> 6;       // 0..3; handles sc0 and sc0+4
#pragma unroll
    for (int q = 0; q < 2; ++q) {
      const int sc = sc0 + q * 4;
      const float* sp = V + src_base + (size_t)(sc * 8) * ROWSTR + e;
      const float v0 = sp[0];
      const float v1 = sp[1 * ROWSTR];
      const float v2 = sp[2 * ROWSTR];
      const float v3 = sp[3 * ROWSTR];
      const float v4 = sp[4 * ROWSTR];
      const float v5 = sp[5 * ROWSTR];
      const float v6 = sp[6 * ROWSTR];
      const float v7 = sp[7 * ROWSTR];
      bfr8 o;
      o.u[0] = pk2(v0, v1); o.u[1] = pk2(v2, v3);
      o.u[2] = pk2(v4, v5); o.u[3] = pk2(v6, v7);
      *reinterpret_cast<bf16x8*>(dst + e * 64 + ((sc ^ (e & 7)) * 8)) = o.v;
    }
  }
}

// ---------------- main attention: 4 independent waves per block, no barriers ----------------
__launch_bounds__(256, 4)
__global__ void geom_attn(const float* __restrict__ Q,
                          const short* __restrict__ Kg,
                          const short* __restrict__ Vg,
                          const float* __restrict__ kn2g,
                          float* __restrict__ out) {
  __shared__ __align__(16) short Plds[4][1024];   // 2 KB per wave, wave-private

  const int tid = threadIdx.x;
  const int lane = tid & 63;
  const int w = tid >> 6;         // 0..3: independent q-tiles, never synced
  const int c = lane & 15;
  const int g = lane >> 4;        // 0..3
  const int cx = c & 7;

  // 1024 blocks; XCD-chunked: each XCD owns 128 consecutive vbk = 4 bh
  // (Kg+Vg+kn working set ~2MB -> resident in that XCD's L2).
  const int vbk = ((blockIdx.x & 7) << 7) + (blockIdx.x >> 3);
  const int qq = vbk & 31;        // q-tile group (4 tiles of 16 rows)
  const int bh = vbk >> 5;
  const int b = bh >> 3, h = bh & 7;
  const int q0 = qq * 64 + w * 16;   // this wave's 16 q-rows

  const size_t qbase = (size_t)b * (L_ * ROWSTR) + (size_t)h * E_;

  // ---- Q fragments (bf16 pairs) + |q|^2 (fp32 exact); lane holds qn2 of q-row q0+c
  bfr8 qa[2];
  float qn2sc;
  {
    const float* qp = Q + qbase + (size_t)(q0 + c) * ROWSTR;
    float qs = 0.f;
#pragma unroll
    for (int ch = 0; ch < 2; ++ch) {
      const float4 a = *reinterpret_cast<const float4*>(qp + ch * 32 + g * 8);
      const float4 b4 = *reinterpret_cast<const float4*>(qp + ch * 32 + g * 8 + 4);
      qa[ch].u[0] = pk2(a.x, a.y);  qa[ch].u[1] = pk2(a.z, a.w);
      qa[ch].u[2] = pk2(b4.x, b4.y); qa[ch].u[3] = pk2(b4.z, b4.w);
      qs += a.x*a.x + a.y*a.y + a.z*a.z + a.w*a.w
          + b4.x*b4.x + b4.y*b4.y + b4.z*b4.z + b4.w*b4.w;
    }
    qs += __shfl_xor(qs, 16);
    qs += __shfl_xor(qs, 32);
    qn2sc = qs;
  }
  const f32x2 qn2v = {qn2sc, qn2sc};
  const f32x2 eps2 = {EPS_, EPS_};
  const f32x2 sc2v = {SC2_, SC2_};

  f32x2 lsA = {0.f, 0.f}, lsB = {0.f, 0.f};
  f32x2 ssA = {0.f, 0.f}, ssB = {0.f, 0.f};
  f32x4 o[4];
#pragma unroll
  for (int dt = 0; dt < 4; ++dt) o[dt] = (f32x4){0.f, 0.f, 0.f, 0.f};

  const short* Ktile = Kg + (size_t)(bh * 32) * 4096;
  const short* Vtile = Vg + (size_t)(bh * 32) * 4096;
  const float* knb = kn2g + (size_t)(bh * 32) * 64;

  for (int kt = 0; kt < 32; ++kt) {
    const short* Kt = Ktile + (size_t)kt * 4096;
    const short* Vt = Vtile + (size_t)kt * 4096;

    // ---- K-phase loads (die before V-phase: keeps peak VGPR low)
    f32x4 kn[4];
#pragma unroll
    for (int sub = 0; sub < 4; ++sub)
      kn[sub] = *reinterpret_cast<const f32x4*>(knb + kt * 64 + sub * 16 + g * 4);

    bf16x8 kf[8];
#pragma unroll
    for (int sub = 0; sub < 4; ++sub)
#pragma unroll
      for (int ch = 0; ch < 2; ++ch)
        kf[sub * 2 + ch] = *reinterpret_cast<const bf16x8*>(
            Kt + (sub * 16 + c) * 64 + (((ch * 4 + g) ^ cx) << 3));

    // ---- swapped QK^T: acc[i] = S[s = sub*16 + g*4 + i][q-row = q0 + c]
#pragma unroll
    for (int sub = 0; sub < 4; ++sub) {
      f32x4 acc = (f32x4){0.f, 0.f, 0.f, 0.f};
      acc = __builtin_amdgcn_mfma_f32_16x16x32_bf16(kf[sub * 2 + 0], qa[0].v, acc, 0, 0, 0);
      acc = __builtin_amdgcn_mfma_f32_16x16x32_bf16(kf[sub * 2 + 1], qa[1].v, acc, 0, 0, 0);
      // packed-f32 score math
      const f32x2 d0 = {acc[0], acc[1]};
      const f32x2 d1 = {acc[2], acc[3]};
      const f32x2 ka = {kn[sub][0], kn[sub][1]};
      const f32x2 kb = {kn[sub][2], kn[sub][3]};
      f32x2 w0 = -d0 * d0 + (qn2v * ka + eps2);
      f32x2 w1 = -d1 * d1 + (qn2v * kb + eps2);
      w0[0] = fmaxf(w0[0], EPS_); w0[1] = fmaxf(w0[1], EPS_);
      w1[0] = fmaxf(w1[0], EPS_); w1[1] = fmaxf(w1[1], EPS_);
      f32x2 s0 = {fast_sqrt(w0[0]), fast_sqrt(w0[1])};
      f32x2 s1 = {fast_sqrt(w1[0]), fast_sqrt(w1[1])};
      s0 *= sc2v; s1 *= sc2v;
      ssA += s0; ssB += s1;
      const f32x2 p0 = {fast_exp2(s0[0]), fast_exp2(s0[1])};
      const f32x2 p1 = {fast_exp2(s1[0]), fast_exp2(s1[1])};
      lsA += p0; lsB += p1;
      uint2 pw;
      pw.x = cvtpk(p0[0], p0[1]);
      pw.y = cvtpk(p1[0], p1[1]);
      // swizzled P store: q-row c, shorts (sub*16+g*4) ^ (cx<<3)
      const int po = c * 64 + ((sub * 16 + g * 4) ^ (cx << 3));
      *reinterpret_cast<uint2*>(&Plds[w][po]) = pw;
    }

    // ---- PV: o[16x64] += P[16x64] @ V[64x64]; V fragments loaded per ks2 group
#pragma unroll
    for (int ks2 = 0; ks2 < 2; ++ks2) {
      bf16x8 vf[4];
#pragma unroll
      for (int dt = 0; dt < 4; ++dt)
        vf[dt] = *reinterpret_cast<const bf16x8*>(
            Vt + (dt * 16 + c) * 64 + (((ks2 * 4 + g) ^ cx) << 3));
      const int pr = c * 64 + ((ks2 * 32 + g * 8) ^ (cx << 3));
      const bf16x8 pa = *reinterpret_cast<const bf16x8*>(&Plds[w][pr]);
#pragma unroll
      for (int dt = 0; dt < 4; ++dt)
        o[dt] = __builtin_amdgcn_mfma_f32_16x16x32_bf16(pa, vf[dt], o[dt], 0, 0, 0);
    }
  }

  // ---- epilogue: finish row-c sum, broadcast row g*4+i's inverse, store
  const f32x2 lsT = lsA + lsB;
  float lsum = lsT[0] + lsT[1];
  lsum += __shfl_xor(lsum, 16);
  lsum += __shfl_xor(lsum, 32);
  const float rinv = 1.0f / lsum;   // 1/rowsum for q-row q0+c

#pragma unroll
  for (int i = 0; i < 4; ++i) {
    const float inv = __shfl(rinv, g * 4 + i);   // lane g*4+i holds row g*4+i
    const int qrow = q0 + g * 4 + i;
    float* op = out + (size_t)b * (L_ * ROWSTR) + (size_t)qrow * ROWSTR + (size_t)h * E_;
#pragma unroll
    for (int dt = 0; dt < 4; ++dt)
      op[dt * 16 + c] = o[dt][i] * inv;
  }

  const f32x2 ssT = ssA + ssB;
  float ssum = ssT[0] + ssT[1];
#pragma unroll
  for (int m = 1; m < 64; m <<= 1) ssum += __shfl_xor(ssum, m);
  if (lane == 0) atomicAdd(out + NOUT, ssum * (LN2_ / 134217728.0f));
}

extern "C" void kernel_launch(void* const* d_in, const int* in_sizes, int n_in,
                              void* d_out, int out_size, void* d_ws, size_t ws_size,
                              hipStream_t stream) {
  const float* Q = (const float*)d_in[0];
  const float* K = (const float*)d_in[1];
  const float* V = (const float*)d_in[2];
  float* out = (float*)d_out;

  short* Kg = (short*)((char*)d_ws + K_OFF);
  short* Vg = (short*)((char*)d_ws + V_OFF);
  float* kn2g = (float*)((char*)d_ws + KN_OFF);

  prep_kv<<<dim3(1024), dim3(256), 0, stream>>>(K, V, Kg, Vg, kn2g, out);
  geom_attn<<<dim3(1024), dim3(256), 0, stream>>>(Q, Kg, Vg, kn2g, out);
}

// Round 9
// 197.501 us; speedup vs baseline: 1.2358x; 1.2358x over previous
//
#include <hip/hip_runtime.h>
#include <hip/hip_bf16.h>

// CombinedGeomAttention, ALPHA=1:
//   s = 0.125*sqrt(relu(|q|^2|k|^2 - (q.k)^2) + 1e-8); out0 = softmax_s(s) @ V; out1 = mean(s)
// Round 9: r6 attention verbatim (best: 108us) but prep rebuilt as near-memcpy:
//   Kg = straight bf16 copy of K (pure stream), Vg = straight bf16 transpose,
//   XOR chunk-swizzle moved into attn's global_load_lds SOURCE addresses
//   (per-lane global addr, linear LDS dest -> identical LDS image as r6).

#define B_ 4
#define L_ 2048
#define S_ 2048
#define H_ 8
#define E_ 64
#define EPS_ 1e-8f
#define SC2_ 0.18033688011112042f   // 0.125 * log2(e)
#define LN2_ 0.6931471805599453f
#define ROWSTR (H_ * E_)            // 512 floats
#define NOUT ((size_t)B_ * L_ * H_ * E_)

#define K_OFF 0
#define V_OFF 8388608
#define KN_OFF 16777216

typedef __attribute__((ext_vector_type(8))) short bf16x8;
typedef __attribute__((ext_vector_type(4))) float f32x4;
typedef __attribute__((ext_vector_type(2))) float f32x2;

union bfr8 { bf16x8 v; unsigned u[4]; };

static __device__ __forceinline__ unsigned pk2(float lo, float hi) {
  union { __hip_bfloat162 h2; unsigned u; } cv;
  cv.h2 = __float22bfloat162_rn(float2{lo, hi});
  return cv.u;
}
static __device__ __forceinline__ unsigned cvtpk(float lo, float hi) {
  unsigned r;
  asm("v_cvt_pk_bf16_f32 %0, %1, %2" : "=v"(r) : "v"(lo), "v"(hi));
  return r;
}
static __device__ __forceinline__ float fast_sqrt(float x) {
  float r; asm("v_sqrt_f32 %0, %1" : "=v"(r) : "v"(x)); return r;
}
static __device__ __forceinline__ float fast_exp2(float x) {
  float r; asm("v_exp_f32 %0, %1" : "=v"(r) : "v"(x)); return r;
}
static __device__ __forceinline__ void gload16(const void* g, void* l) {
  __builtin_amdgcn_global_load_lds((const __attribute__((address_space(1))) void*)g,
                                   (__attribute__((address_space(3))) void*)l, 16, 0, 0);
}

// ---------------- prep ----------------
// blocks 0..1023:    (bh,st): Vg[bh][st][e][s] = bf16(V) straight transpose
//                    + kn2g[bh*32+st][s] = |k_s|^2 (fp32, from K tile)
// blocks 1024..2047: Kg = bf16(K) pure linear stream (same [b][s][h][e] layout)
__global__ void prep_kv(const float* __restrict__ K, const float* __restrict__ V,
                        short* __restrict__ Kg, short* __restrict__ Vg,
                        float* __restrict__ kn2g, float* __restrict__ out) {
  const int tid = threadIdx.x;
  const int bidx = blockIdx.x;
  if (bidx == 0 && tid == 0) out[NOUT] = 0.f;   // zero the scalar accumulator slot

  if (bidx >= 1024) {
    // ---- K: pure streaming fp32 -> bf16 (4096 floats per block)
    const int kidx = bidx - 1024;
    const size_t base = (size_t)kidx * 4096 + (size_t)tid * 8;
#pragma unroll
    for (int it = 0; it < 2; ++it) {
      const size_t idx = base + (size_t)it * 2048;
      const float4 a = *reinterpret_cast<const float4*>(K + idx);
      const float4 c4 = *reinterpret_cast<const float4*>(K + idx + 4);
      bfr8 o;
      o.u[0] = pk2(a.x, a.y);  o.u[1] = pk2(a.z, a.w);
      o.u[2] = pk2(c4.x, c4.y); o.u[3] = pk2(c4.z, c4.w);
      *reinterpret_cast<bf16x8*>(Kg + idx) = o.v;
    }
    return;
  }

  const int st = bidx & 31;
  const int bh = bidx >> 5;
  const int b = bh >> 3, h = bh & 7;
  const size_t src_base = (size_t)b * (L_ * ROWSTR) + (size_t)(st * 64) * ROWSTR + (size_t)h * E_;

  // ---- kn2 from K tile (64B-contiguous segments: 4 lanes/row x 4 float4)
  {
    const int s = tid >> 2;
    const int f = tid & 3;
    const float* sp = K + src_base + (size_t)s * ROWSTR;
    float part = 0.f;
#pragma unroll
    for (int j = 0; j < 4; ++j) {
      const float4 a = *reinterpret_cast<const float4*>(sp + f * 4 + j * 16);
      part += a.x*a.x + a.y*a.y + a.z*a.z + a.w*a.w;
    }
    part += __shfl_xor(part, 1);
    part += __shfl_xor(part, 2);
    if (f == 0) kn2g[(size_t)bidx * 64 + s] = part;
  }

  // ---- V: straight bf16 transpose [e][s] (no swizzle; coalesced column reads)
  {
    short* dst = Vg + (size_t)bidx * 4096;
    const int e = tid & 63;
    const int sc0 = tid >> 6;       // 0..3; handles sc0 and sc0+4
#pragma unroll
    for (int q = 0; q < 2; ++q) {
      const int sc = sc0 + q * 4;
      const float* sp = V + src_base + (size_t)(sc * 8) * ROWSTR + e;
      const float v0 = sp[0];
      const float v1 = sp[1 * ROWSTR];
      const float v2 = sp[2 * ROWSTR];
      const float v3 = sp[3 * ROWSTR];
      const float v4 = sp[4 * ROWSTR];
      const float v5 = sp[5 * ROWSTR];
      const float v6 = sp[6 * ROWSTR];
      const float v7 = sp[7 * ROWSTR];
      bfr8 o;
      o.u[0] = pk2(v0, v1); o.u[1] = pk2(v2, v3);
      o.u[2] = pk2(v4, v5); o.u[3] = pk2(v6, v7);
      *reinterpret_cast<bf16x8*>(dst + e * 64 + sc * 8) = o.v;
    }
  }
}

// ---------------- main attention (r6 structure; swizzle moved to gload source) ----------------
__launch_bounds__(256, 4)
__global__ void geom_attn(const float* __restrict__ Q,
                          const short* __restrict__ Kg,
                          const short* __restrict__ Vg,
                          const float* __restrict__ kn2g,
                          float* __restrict__ out) {
  __shared__ __align__(16) short Kl[2][4096];   // 16 KB
  __shared__ __align__(16) short Vl[2][4096];   // 16 KB
  __shared__ __align__(16) short Plds[4][1024]; //  8 KB (compact, swizzled)

  const int tid = threadIdx.x;
  const int lane = tid & 63;
  const int w = tid >> 6;       // 0..3
  const int g = lane >> 4;      // 0..3
  const int c = lane & 15;
  const int cx = c & 7;

  // XCD-chunked swizzle: 1024 blocks; each XCD owns 4 consecutive bh
  const int vbk = ((blockIdx.x & 7) << 7) + (blockIdx.x >> 3);
  const int qt = vbk & 31;
  const int bh = vbk >> 5;
  const int b = bh >> 3, h = bh & 7;
  const int q0 = qt * 64;

  const size_t qbase = (size_t)b * (L_ * ROWSTR) + (size_t)h * E_;

  // ---- Q fragments (bf16 pairs) + |q|^2 (fp32 exact); lane holds qn2 of q-row w*16+c
  bfr8 qa[2];
  float qn2sc;
  {
    const int qrow = q0 + w * 16 + c;
    const float* qp = Q + qbase + (size_t)qrow * ROWSTR;
    float qs = 0.f;
#pragma unroll
    for (int ch = 0; ch < 2; ++ch) {
      const float4 a = *reinterpret_cast<const float4*>(qp + ch * 32 + g * 8);
      const float4 b4 = *reinterpret_cast<const float4*>(qp + ch * 32 + g * 8 + 4);
      qa[ch].u[0] = pk2(a.x, a.y);  qa[ch].u[1] = pk2(a.z, a.w);
      qa[ch].u[2] = pk2(b4.x, b4.y); qa[ch].u[3] = pk2(b4.z, b4.w);
      qs += a.x*a.x + a.y*a.y + a.z*a.z + a.w*a.w
          + b4.x*b4.x + b4.y*b4.y + b4.z*b4.z + b4.w*b4.w;
    }
    qs += __shfl_xor(qs, 16);
    qs += __shfl_xor(qs, 32);
    qn2sc = qs;
  }
  const f32x2 qn2v = {qn2sc, qn2sc};
  const f32x2 eps2 = {EPS_, EPS_};
  const f32x2 sc2v = {SC2_, SC2_};

  f32x2 lsA = {0.f, 0.f}, lsB = {0.f, 0.f};
  f32x2 ssA = {0.f, 0.f}, ssB = {0.f, 0.f};
  f32x4 o[4];
#pragma unroll
  for (int dt = 0; dt < 4; ++dt) o[dt] = (f32x4){0.f, 0.f, 0.f, 0.f};

  // ---- per-lane pre-swizzled global source addresses (m173 pattern):
  // LDS dest is linear (wb + lane*16, +1024); the source chunk index carries the
  // XOR so the LDS image equals r6's swizzled layout exactly.
  const int lr = lane >> 3;       // dest row within the 8-row group
  const int lch = lane & 7;       // dest 16B chunk
  const int kr1 = w * 16 + lr;    // K dest rows kr1, kr1+8  (s-rows)
  const int kr2 = kr1 + 8;
  // K straight layout: [b][s][h][e] bf16; row stride 512 shorts; tile stride 64*512
  const short* Kbh = Kg + (size_t)b * (L_ * ROWSTR) + (size_t)h * E_;
  const short* ks1 = Kbh + (size_t)(q0 * 0 + kr1) * ROWSTR + ((lch ^ (kr1 & 7)) << 3);
  const short* ks2 = Kbh + (size_t)kr2 * ROWSTR + ((lch ^ (kr2 & 7)) << 3);
  // V transposed layout: [bh][st][e][s] bf16; e-row stride 64 shorts; tile stride 4096
  const short* Vbh = Vg + (size_t)bh * (32 * 4096);
  const short* vs1 = Vbh + (size_t)kr1 * 64 + ((lch ^ (kr1 & 7)) << 3);
  const short* vs2 = Vbh + (size_t)kr2 * 64 + ((lch ^ (kr2 & 7)) << 3);

  const float* knb = kn2g + (size_t)(bh * 32) * 64;
  const int wb = w * 2048;  // wave's byte range within an 8KB LDS tile

  f32x4 kn_cur[4], kn_nx[4];
#pragma unroll
  for (int sub = 0; sub < 4; ++sub)
    kn_cur[sub] = *reinterpret_cast<const f32x4*>(knb + sub * 16 + g * 4);

  // prologue: stage K[0], V[0] into buffer 0
  gload16(ks1, (char*)&Kl[0][0] + wb + lane * 16);
  gload16(ks2, (char*)&Kl[0][0] + wb + 1024 + lane * 16);
  gload16(vs1, (char*)&Vl[0][0] + wb + lane * 16);
  gload16(vs2, (char*)&Vl[0][0] + wb + 1024 + lane * 16);

  for (int kt = 0; kt < 32; ++kt) {
    const int cb = kt & 1;
    const int nx = (kt + 1) & 31;     // wrap: harmless extra prefetch on last iter
    __syncthreads();   // full drain: K[kt],V[kt] staged; bufs cb^1 free

    // prefetch tile kt+1 (has the whole compute phase to land)
#pragma unroll
    for (int sub = 0; sub < 4; ++sub)
      kn_nx[sub] = *reinterpret_cast<const f32x4*>(knb + nx * 64 + sub * 16 + g * 4);
    gload16(vs1 + (size_t)nx * 4096, (char*)&Vl[cb ^ 1][0] + wb + lane * 16);
    gload16(vs2 + (size_t)nx * 4096, (char*)&Vl[cb ^ 1][0] + wb + 1024 + lane * 16);
    gload16(ks1 + (size_t)nx * (64 * ROWSTR), (char*)&Kl[cb ^ 1][0] + wb + lane * 16);
    gload16(ks2 + (size_t)nx * (64 * ROWSTR), (char*)&Kl[cb ^ 1][0] + wb + 1024 + lane * 16);
    __builtin_amdgcn_sched_barrier(0);  // pin prefetch issue before compute

    // ---- swapped QK^T: acc[i] = S[s = sub*16 + g*4 + i][qrow = w*16 + c]
#pragma unroll
    for (int sub = 0; sub < 4; ++sub) {
      f32x4 acc = (f32x4){0.f, 0.f, 0.f, 0.f};
#pragma unroll
      for (int ch = 0; ch < 2; ++ch) {
        const int idx = (sub * 16 + c) * 64 + (((ch * 4 + g) ^ cx) << 3);
        const bf16x8 kh8 = *reinterpret_cast<const bf16x8*>(&Kl[cb][idx]);
        acc = __builtin_amdgcn_mfma_f32_16x16x32_bf16(kh8, qa[ch].v, acc, 0, 0, 0);
      }
      // packed-f32 score math
      const f32x2 d0 = {acc[0], acc[1]};
      const f32x2 d1 = {acc[2], acc[3]};
      const f32x2 ka = {kn_cur[sub][0], kn_cur[sub][1]};
      const f32x2 kb = {kn_cur[sub][2], kn_cur[sub][3]};
      f32x2 w0 = -d0 * d0 + (qn2v * ka + eps2);
      f32x2 w1 = -d1 * d1 + (qn2v * kb + eps2);
      w0[0] = fmaxf(w0[0], EPS_); w0[1] = fmaxf(w0[1], EPS_);
      w1[0] = fmaxf(w1[0], EPS_); w1[1] = fmaxf(w1[1], EPS_);
      f32x2 s0 = {fast_sqrt(w0[0]), fast_sqrt(w0[1])};
      f32x2 s1 = {fast_sqrt(w1[0]), fast_sqrt(w1[1])};
      s0 *= sc2v; s1 *= sc2v;
      ssA += s0; ssB += s1;
      const f32x2 p0 = {fast_exp2(s0[0]), fast_exp2(s0[1])};
      const f32x2 p1 = {fast_exp2(s1[0]), fast_exp2(s1[1])};
      lsA += p0; lsB += p1;
      uint2 pw;
      pw.x = cvtpk(p0[0], p0[1]);
      pw.y = cvtpk(p1[0], p1[1]);
      // compact swizzled P store: q-row c, shorts (sub*16+g*4) ^ (cx<<3)
      const int po = c * 64 + ((sub * 16 + g * 4) ^ (cx << 3));
      *reinterpret_cast<uint2*>(&Plds[w][po]) = pw;
    }

    // ---- PV: o[16x64] += P[16x64] @ V[64x64]
    __builtin_amdgcn_s_setprio(1);
#pragma unroll
    for (int ks2i = 0; ks2i < 2; ++ks2i) {
      const int pr = c * 64 + ((ks2i * 32 + g * 8) ^ (cx << 3));
      const bf16x8 pa = *reinterpret_cast<const bf16x8*>(&Plds[w][pr]);
#pragma unroll
      for (int dt = 0; dt < 4; ++dt) {
        const int idx = (dt * 16 + c) * 64 + (((ks2i * 4 + g) ^ cx) << 3);
        const bf16x8 vb8 = *reinterpret_cast<const bf16x8*>(&Vl[cb][idx]);
        o[dt] = __builtin_amdgcn_mfma_f32_16x16x32_bf16(pa, vb8, o[dt], 0, 0, 0);
      }
    }
    __builtin_amdgcn_s_setprio(0);
#pragma unroll
    for (int sub = 0; sub < 4; ++sub) kn_cur[sub] = kn_nx[sub];
  }

  // ---- epilogue: finish row-c sum, broadcast row g*4+i's inverse, store
  const f32x2 lsT = lsA + lsB;
  float lsum = lsT[0] + lsT[1];
  lsum += __shfl_xor(lsum, 16);
  lsum += __shfl_xor(lsum, 32);
  const float rinv = 1.0f / lsum;   // 1/rowsum for q-row (w*16 + c)

#pragma unroll
  for (int i = 0; i < 4; ++i) {
    const float inv = __shfl(rinv, g * 4 + i);   // lane g*4+i holds row g*4+i
    const int qrow = q0 + w * 16 + g * 4 + i;
    float* op = out + (size_t)b * (L_ * ROWSTR) + (size_t)qrow * ROWSTR + (size_t)h * E_;
#pragma unroll
    for (int dt = 0; dt < 4; ++dt)
      op[dt * 16 + c] = o[dt][i] * inv;
  }

  const f32x2 ssT = ssA + ssB;
  float ssum = ssT[0] + ssT[1];
#pragma unroll
  for (int m = 1; m < 64; m <<= 1) ssum += __shfl_xor(ssum, m);
  if (lane == 0) atomicAdd(out + NOUT, ssum * (LN2_ / 134217728.0f));
}

extern "C" void kernel_launch(void* const* d_in, const int* in_sizes, int n_in,
                              void* d_out, int out_size, void* d_ws, size_t ws_size,
                              hipStream_t stream) {
  const float* Q = (const float*)d_in[0];
  const float* K = (const float*)d_in[1];
  const float* V = (const float*)d_in[2];
  float* out = (float*)d_out;

  short* Kg = (short*)((char*)d_ws + K_OFF);
  short* Vg = (short*)((char*)d_ws + V_OFF);
  float* kn2g = (float*)((char*)d_ws + KN_OFF);

  prep_kv<<<dim3(2048), dim3(256), 0, stream>>>(K, V, Kg, Vg, kn2g, out);
  geom_attn<<<dim3(1024), dim3(256), 0, stream>>>(Q, Kg, Vg, kn2g, out);
}